// Round 1
// baseline (727.465 us; speedup 1.0000x reference)
//
#include <hip/hip_runtime.h>
#include <hip/hip_bf16.h>
#include <stdint.h>

// Problem constants (fixed by setup_inputs): B=4,S=2048 -> T=8192, D=1024, H=2048, E=8, topk=2
#define T_TOK   8192
#define D_DIM   1024
#define H_DIM   2048
#define E_EXP   8
#define NP2     4096                    // interleaved w1/w2 rows = 2*H
#define BM      128                     // GEMM M-tile; expert regions 128-aligned
#define CAP     (2*T_TOK + E_EXP*BM)    // 17408 padded slots
#define MAXMB   (CAP/BM)                // 136 max m-blocks

using f32x4 = __attribute__((ext_vector_type(4))) float;
using s16x4 = __attribute__((ext_vector_type(4))) short;
using s16x8 = __attribute__((ext_vector_type(8))) short;   // 8 bf16 = 4 VGPRs (MFMA A/B frag)

__device__ __forceinline__ short bf16_of(float f) {
  union { float f; unsigned u; } v; v.f = f;
  unsigned r = v.u + 0x7FFFu + ((v.u >> 16) & 1u);          // round-to-nearest-even
  return (short)(r >> 16);
}
__device__ __forceinline__ float f_of_bf16(short s) {
  union { unsigned u; float f; } v; v.u = ((unsigned)(unsigned short)s) << 16;
  return v.f;
}

// async global->LDS, 16B per lane (wave-uniform LDS base + lane*16)
__device__ __forceinline__ void gload16(const void* g, void* l) {
  __builtin_amdgcn_global_load_lds(
      (const __attribute__((address_space(1))) unsigned int*)g,
      (__attribute__((address_space(3))) unsigned int*)l, 16, 0, 0);
}

// ---------------- weight conversion ----------------
// w12b layout: [e][n'][k], n' = g*32 + half*16 + s  ->  (half?w2:w1)[e][g*16+s][k]
// so in a 128-col GEMM tile, 16-col fragments alternate a1/a2 and pair up in-lane.
__global__ __launch_bounds__(256) void conv_w12(const float* __restrict__ w1,
                                                const float* __restrict__ w2,
                                                short* __restrict__ w12b) {
  int idx = blockIdx.x * 256 + threadIdx.x;        // over E*4096*256 f32x4 units
  int e = idx >> 20;
  int rem = idx & 0xFFFFF;
  int np = rem >> 8;
  int kc = rem & 255;
  int g = np >> 5, tt = np & 31, half = tt >> 4, srow = g * 16 + (tt & 15);
  const f32x4* src = (const f32x4*)(half ? w2 : w1) + ((size_t)e * H_DIM + srow) * 256 + kc;
  f32x4 v = *src;
  s16x4 o;
  o[0] = bf16_of(v[0]); o[1] = bf16_of(v[1]); o[2] = bf16_of(v[2]); o[3] = bf16_of(v[3]);
  ((s16x4*)w12b)[idx] = o;
}

__global__ __launch_bounds__(256) void conv_w3(const float* __restrict__ w3,
                                               short* __restrict__ w3b) {
  int idx = blockIdx.x * 256 + threadIdx.x;        // over E*1024*512 f32x4 units
  f32x4 v = ((const f32x4*)w3)[idx];
  s16x4 o;
  o[0] = bf16_of(v[0]); o[1] = bf16_of(v[1]); o[2] = bf16_of(v[2]); o[3] = bf16_of(v[3]);
  ((s16x4*)w3b)[idx] = o;
}

// ---------------- gating ----------------
__global__ __launch_bounds__(256) void gate_kernel(const float* __restrict__ x,
                                                   const float* __restrict__ gw,
                                                   int* __restrict__ counts,
                                                   int* __restrict__ tok_e,
                                                   float* __restrict__ gatew) {
  __shared__ float g[E_EXP * D_DIM];               // 32 KiB
  int tid = threadIdx.x;
  for (int i = tid; i < E_EXP * 256; i += 256)
    ((f32x4*)g)[i] = ((const f32x4*)gw)[i];
  __syncthreads();
  int w = tid >> 6, lane = tid & 63;
  int t = blockIdx.x * 4 + w;
  float acc[E_EXP] = {};
  const f32x4* xrow = (const f32x4*)(x + (size_t)t * D_DIM);
#pragma unroll
  for (int i = 0; i < 4; ++i) {
    f32x4 xv = xrow[lane + 64 * i];
#pragma unroll
    for (int e = 0; e < E_EXP; ++e) {
      f32x4 gv = ((const f32x4*)g)[e * 256 + lane + 64 * i];
      acc[e] += xv[0] * gv[0] + xv[1] * gv[1] + xv[2] * gv[2] + xv[3] * gv[3];
    }
  }
#pragma unroll
  for (int e = 0; e < E_EXP; ++e)
#pragma unroll
    for (int off = 1; off < 64; off <<= 1)
      acc[e] += __shfl_xor(acc[e], off);
  if (lane == 0) {
    int i0 = 0; float v0 = acc[0];
    for (int e = 1; e < E_EXP; ++e) if (acc[e] > v0) { v0 = acc[e]; i0 = e; }   // ties: lower idx (jax)
    int i1 = -1; float v1 = -1e30f;
    for (int e = 0; e < E_EXP; ++e) if (e != i0 && acc[e] > v1) { v1 = acc[e]; i1 = e; }
    float z = __expf(v1 - v0);
    tok_e[2 * t] = i0; tok_e[2 * t + 1] = i1;
    gatew[2 * t] = 1.f / (1.f + z); gatew[2 * t + 1] = z / (1.f + z);
    atomicAdd(&counts[i0], 1); atomicAdd(&counts[i1], 1);
  }
}

// ---------------- routing metadata ----------------
__global__ void scan_kernel(const int* __restrict__ counts, int* __restrict__ off,
                            int* __restrict__ mb2e, int* __restrict__ mb2row) {
  if (threadIdx.x == 0 && blockIdx.x == 0) {
    int acc = 0, mb = 0;
    for (int e = 0; e < E_EXP; ++e) {
      off[e] = acc;
      int nb = (counts[e] + BM - 1) / BM;
      for (int b = 0; b < nb; ++b) { mb2e[mb] = e; mb2row[mb] = acc + b * BM; ++mb; }
      acc += nb * BM;
    }
    off[E_EXP] = acc;
    for (; mb < MAXMB; ++mb) mb2e[mb] = -1;
  }
}

__global__ __launch_bounds__(256) void assign_kernel(const int* __restrict__ tok_e,
                                                     const int* __restrict__ off,
                                                     int* __restrict__ fill,
                                                     int* __restrict__ perm,
                                                     int* __restrict__ tok_slot) {
  int t = blockIdx.x * 256 + threadIdx.x;
  if (t >= T_TOK) return;
#pragma unroll
  for (int k = 0; k < 2; ++k) {
    int e = tok_e[2 * t + k];
    int pos = atomicAdd(&fill[e], 1);
    int slot = off[e] + pos;                       // slot order nondet, values per-token det
    perm[slot] = t;
    tok_slot[2 * t + k] = slot;
  }
}

// ---------------- gather tokens -> contiguous bf16 rows per expert ----------------
__global__ __launch_bounds__(128) void gather_kernel(const float* __restrict__ x,
                                                     const int* __restrict__ off,
                                                     const int* __restrict__ counts,
                                                     const int* __restrict__ perm,
                                                     short* __restrict__ Xp) {
  int s = blockIdx.x, tid = threadIdx.x;
  int e = -1;
#pragma unroll
  for (int i = 0; i < E_EXP; ++i)
    if (s >= off[i] && s < off[i + 1]) { e = i; break; }
  bool valid = false; int t = 0;
  if (e >= 0) { int r = s - off[e]; if (r < counts[e]) { valid = true; t = perm[s]; } }
  s16x8 o;
  if (valid) {
    const f32x4* xr = (const f32x4*)(x + (size_t)t * D_DIM);
    f32x4 a = xr[tid * 2], b = xr[tid * 2 + 1];
    o[0] = bf16_of(a[0]); o[1] = bf16_of(a[1]); o[2] = bf16_of(a[2]); o[3] = bf16_of(a[3]);
    o[4] = bf16_of(b[0]); o[5] = bf16_of(b[1]); o[6] = bf16_of(b[2]); o[7] = bf16_of(b[3]);
  } else {
#pragma unroll
    for (int j = 0; j < 8; ++j) o[j] = 0;          // zero pad rows
  }
  *(s16x8*)(Xp + (size_t)s * D_DIM + tid * 8) = o;
}

// ---------------- GEMM (m97 structure: 128x128 tile, BK=64, global_load_lds + XOR swizzle) ----
// C[m][n] = sum_k A[m][k]*B[n][k] (both row-major, K contiguous, bf16).
// EPI=0: B=w12b interleaved, epilogue h=(a1+b1)*silu(a2+b2) -> h bf16 [slot][H]
// EPI=1: B=w3b,              epilogue y=acc+b3            -> ys bf16 [slot][D]
template <int K, int EPI>
__global__ __launch_bounds__(256) void gemm_bt(const short* __restrict__ A,
                                               const short* __restrict__ Bw,
                                               const int* __restrict__ mb2e,
                                               const int* __restrict__ mb2row,
                                               const float* __restrict__ biasA,
                                               const float* __restrict__ biasB,
                                               short* __restrict__ Out) {
  constexpr int NFULL = (EPI == 0) ? NP2 : D_DIM;
  constexpr int OUTLD = (EPI == 0) ? H_DIM : D_DIM;
  constexpr int KBYTES = K * 2;
  constexpr int KT = K / 64;

  const int mb = blockIdx.y;
  const int e = mb2e[mb];
  if (e < 0) return;
  const int row0 = mb2row[mb];
  const int bn = blockIdx.x;

  __shared__ alignas(16) char sA[16384];           // 128 rows x 128B (BK=64 bf16)
  __shared__ alignas(16) char sB[16384];

  const int tid = threadIdx.x;
  const int lane = tid & 63;
  const int wid = tid >> 6;
  const int wr = wid >> 1, wc = wid & 1;           // 2x2 waves, 64x64 out each

  const char* gA = (const char*)(A + (size_t)row0 * K);
  const char* gB = (const char*)(Bw + ((size_t)e * NFULL + (size_t)bn * BM) * K);

  f32x4 acc[4][4] = {};

  for (int kt = 0; kt < KT; ++kt) {
    // stage: LDS physical p holds logical q = p ^ ((row&7)<<4)  (rule-21: pre-swizzled source)
#pragma unroll
    for (int i = 0; i < 4; ++i) {
      const int p = i * 4096 + tid * 16;
      const int row = p >> 7;
      const int kb = (p & 127) ^ ((row & 7) << 4);
      gload16(gA + (size_t)row * KBYTES + kt * 128 + kb, sA + p);
      gload16(gB + (size_t)row * KBYTES + kt * 128 + kb, sB + p);
    }
    asm volatile("s_waitcnt vmcnt(0)" ::: "memory");
    __syncthreads();
#pragma unroll
    for (int ks = 0; ks < 2; ++ks) {
      s16x8 av[4], bv[4];
      const int kb = ks * 64 + ((lane >> 4) << 4); // lane>>4 -> k-offset {0,8,16,24} elems
#pragma unroll
      for (int f = 0; f < 4; ++f) {
        const int ra = wr * 64 + f * 16 + (lane & 15);
        av[f] = *(const s16x8*)(sA + ra * 128 + (kb ^ ((ra & 7) << 4)));
        const int rb = wc * 64 + f * 16 + (lane & 15);
        bv[f] = *(const s16x8*)(sB + rb * 128 + (kb ^ ((rb & 7) << 4)));
      }
#pragma unroll
      for (int mf = 0; mf < 4; ++mf)
#pragma unroll
        for (int nf = 0; nf < 4; ++nf)
          acc[mf][nf] = __builtin_amdgcn_mfma_f32_16x16x32_bf16(av[mf], bv[nf], acc[mf][nf], 0, 0, 0);
    }
    __syncthreads();
  }

  // epilogue: C/D layout col=lane&15, row=(lane>>4)*4+j  [m89/m91 verified]
  if constexpr (EPI == 0) {
#pragma unroll
    for (int mf = 0; mf < 4; ++mf) {
      const int mrow = row0 + wr * 64 + mf * 16 + ((lane >> 4) << 2);
#pragma unroll
      for (int p = 0; p < 2; ++p) {                // frag pair (2p=a1, 2p+1=a2)
        const int hcol = bn * 64 + wc * 32 + p * 16 + (lane & 15);
        const float bb1 = biasA[e * H_DIM + hcol];
        const float bb2 = biasB[e * H_DIM + hcol];
        const f32x4 a1 = acc[mf][2 * p], a2 = acc[mf][2 * p + 1];
#pragma unroll
        for (int j = 0; j < 4; ++j) {
          float x1 = a1[j] + bb1, x2 = a2[j] + bb2;
          float hv = x1 * (x2 / (1.f + __expf(-x2)));   // x1 * silu(x2)
          Out[(size_t)(mrow + j) * OUTLD + hcol] = bf16_of(hv);
        }
      }
    }
  } else {
#pragma unroll
    for (int mf = 0; mf < 4; ++mf) {
      const int mrow = row0 + wr * 64 + mf * 16 + ((lane >> 4) << 2);
#pragma unroll
      for (int nf = 0; nf < 4; ++nf) {
        const int col = bn * BM + wc * 64 + nf * 16 + (lane & 15);
        const float bb = biasA[e * D_DIM + col];
#pragma unroll
        for (int j = 0; j < 4; ++j)
          Out[(size_t)(mrow + j) * OUTLD + col] = bf16_of(acc[mf][nf][j] + bb);
      }
    }
  }
}

// ---------------- combine: out[t] = w0*ys[slot0] + w1*ys[slot1] ----------------
__global__ __launch_bounds__(128) void combine_kernel(const short* __restrict__ ysb,
                                                      const int* __restrict__ tok_slot,
                                                      const float* __restrict__ gatew,
                                                      float* __restrict__ out) {
  int t = blockIdx.x, tid = threadIdx.x;
  int s0 = tok_slot[2 * t], s1 = tok_slot[2 * t + 1];
  float w0 = gatew[2 * t], w1 = gatew[2 * t + 1];
  s16x8 a = *(const s16x8*)(ysb + (size_t)s0 * D_DIM + tid * 8);
  s16x8 b = *(const s16x8*)(ysb + (size_t)s1 * D_DIM + tid * 8);
  float* op = out + (size_t)t * D_DIM + tid * 8;
  f32x4 o0, o1;
#pragma unroll
  for (int j = 0; j < 4; ++j) o0[j] = w0 * f_of_bf16(a[j]) + w1 * f_of_bf16(b[j]);
#pragma unroll
  for (int j = 0; j < 4; ++j) o1[j] = w0 * f_of_bf16(a[4 + j]) + w1 * f_of_bf16(b[4 + j]);
  *(f32x4*)op = o0;
  *(f32x4*)(op + 4) = o1;
}

// ---------------- launcher ----------------
extern "C" void kernel_launch(void* const* d_in, const int* in_sizes, int n_in,
                              void* d_out, int out_size, void* d_ws, size_t ws_size,
                              hipStream_t stream) {
  const float* x  = (const float*)d_in[0];
  const float* gw = (const float*)d_in[1];
  const float* w1 = (const float*)d_in[2];
  const float* b1 = (const float*)d_in[3];
  const float* w2 = (const float*)d_in[4];
  const float* b2 = (const float*)d_in[5];
  const float* w3 = (const float*)d_in[6];
  const float* b3 = (const float*)d_in[7];
  float* out = (float*)d_out;

  char* ws = (char*)d_ws;
  size_t o = 0;
  short* w12b = (short*)(ws + o); o += (size_t)E_EXP * NP2 * D_DIM * 2;      //  67,108,864
  short* w3b  = (short*)(ws + o); o += (size_t)E_EXP * D_DIM * H_DIM * 2;    //  33,554,432
  short* Xp   = (short*)(ws + o); o += (size_t)CAP * D_DIM * 2;              //  35,651,584
  short* hbuf = (short*)(ws + o); o += (size_t)CAP * H_DIM * 2;              //  71,303,168
  short* ysb  = (short*)(ws + o); o += (size_t)CAP * D_DIM * 2;              //  35,651,584
  int* meta     = (int*)(ws + o);
  int* counts   = meta;            // 8
  int* fill     = meta + 8;        // 8
  int* offv     = meta + 16;       // 9 (pad to 16)
  int* mb2e     = meta + 32;       // 136 (pad to 144)
  int* mb2row   = meta + 176;      // 136 (pad to 144)
  int* tok_e    = meta + 320;      // 2T
  int* tok_slot = tok_e + 2 * T_TOK;
  int* perm     = tok_slot + 2 * T_TOK;             // CAP
  float* gatew  = (float*)(perm + CAP);             // 2T
  const size_t ws_needed = o + (320 + 4 * T_TOK + CAP + 2 * T_TOK) * sizeof(int);
  if (ws_size < ws_needed) return;   // loudly fail validation rather than corrupt

  hipMemsetAsync(counts, 0, 16 * sizeof(int), stream);  // counts + fill

  conv_w12<<<(E_EXP * NP2 * 256) / 256, 256, 0, stream>>>(w1, w2, w12b);
  conv_w3 <<<(E_EXP * D_DIM * (H_DIM / 4)) / 256, 256, 0, stream>>>(w3, w3b);
  gate_kernel<<<T_TOK / 4, 256, 0, stream>>>(x, gw, counts, tok_e, gatew);
  scan_kernel<<<1, 64, 0, stream>>>(counts, offv, mb2e, mb2row);
  assign_kernel<<<T_TOK / 256, 256, 0, stream>>>(tok_e, offv, fill, perm, tok_slot);
  gather_kernel<<<CAP, 128, 0, stream>>>(x, offv, counts, perm, Xp);
  gemm_bt<D_DIM, 0><<<dim3(NP2 / BM, MAXMB), 256, 0, stream>>>(Xp, w12b, mb2e, mb2row, b1, b2, hbuf);
  gemm_bt<H_DIM, 1><<<dim3(D_DIM / BM, MAXMB), 256, 0, stream>>>(hbuf, w3b, mb2e, mb2row, b3, b3, ysb);
  combine_kernel<<<T_TOK, 128, 0, stream>>>(ysb, tok_slot, gatew, out);
}

// Round 2
// 635.291 us; speedup vs baseline: 1.1451x; 1.1451x over previous
//
#include <hip/hip_runtime.h>
#include <hip/hip_bf16.h>
#include <stdint.h>

// Problem constants: B=4,S=2048 -> T=8192, D=1024, H=2048, E=8, topk=2
#define T_TOK   8192
#define D_DIM   1024
#define H_DIM   2048
#define E_EXP   8
#define NP2     4096                    // interleaved w1/w2 rows = 2*H
#define BM      256                     // GEMM M/N tile; expert regions 256-aligned
#define CAP     (2*T_TOK + E_EXP*BM)    // 18432 padded slots
#define MAXMB   (CAP/BM)                // 72 max m-blocks

using f32x4 = __attribute__((ext_vector_type(4))) float;
using s16x4 = __attribute__((ext_vector_type(4))) short;
using s16x8 = __attribute__((ext_vector_type(8))) short;   // 8 bf16 (MFMA A/B frag)

__device__ __forceinline__ short bf16_of(float f) {
  union { float f; unsigned u; } v; v.f = f;
  unsigned r = v.u + 0x7FFFu + ((v.u >> 16) & 1u);          // RNE
  return (short)(r >> 16);
}
__device__ __forceinline__ float f_of_bf16(short s) {
  union { unsigned u; float f; } v; v.u = ((unsigned)(unsigned short)s) << 16;
  return v.f;
}

__device__ __forceinline__ void gload16(const void* g, void* l) {
  __builtin_amdgcn_global_load_lds(
      (const __attribute__((address_space(1))) unsigned int*)g,
      (__attribute__((address_space(3))) unsigned int*)l, 16, 0, 0);
}

// ---------------- weight conversion ----------------
// w12b layout: [e][n'][k], n' = g*32 + half*16 + s -> (half?w2:w1)[e][g*16+s][k]
__global__ __launch_bounds__(256) void conv_w12(const float* __restrict__ w1,
                                                const float* __restrict__ w2,
                                                short* __restrict__ w12b) {
  int idx = blockIdx.x * 256 + threadIdx.x;        // over E*4096*256 f32x4 units
  int e = idx >> 20;
  int rem = idx & 0xFFFFF;
  int np = rem >> 8;
  int kc = rem & 255;
  int g = np >> 5, tt = np & 31, half = tt >> 4, srow = g * 16 + (tt & 15);
  const f32x4* src = (const f32x4*)(half ? w2 : w1) + ((size_t)e * H_DIM + srow) * 256 + kc;
  f32x4 v = *src;
  s16x4 o;
  o[0] = bf16_of(v[0]); o[1] = bf16_of(v[1]); o[2] = bf16_of(v[2]); o[3] = bf16_of(v[3]);
  ((s16x4*)w12b)[idx] = o;
}

__global__ __launch_bounds__(256) void conv_w3(const float* __restrict__ w3,
                                               short* __restrict__ w3b) {
  int idx = blockIdx.x * 256 + threadIdx.x;        // over E*1024*512 f32x4 units
  f32x4 v = ((const f32x4*)w3)[idx];
  s16x4 o;
  o[0] = bf16_of(v[0]); o[1] = bf16_of(v[1]); o[2] = bf16_of(v[2]); o[3] = bf16_of(v[3]);
  ((s16x4*)w3b)[idx] = o;
}

// ---------------- gating ----------------
__global__ __launch_bounds__(256) void gate_kernel(const float* __restrict__ x,
                                                   const float* __restrict__ gw,
                                                   int* __restrict__ counts,
                                                   int* __restrict__ tok_e,
                                                   float* __restrict__ gatew) {
  __shared__ float g[E_EXP * D_DIM];               // 32 KiB
  int tid = threadIdx.x;
  for (int i = tid; i < E_EXP * 256; i += 256)
    ((f32x4*)g)[i] = ((const f32x4*)gw)[i];
  __syncthreads();
  int w = tid >> 6, lane = tid & 63;
  int t = blockIdx.x * 4 + w;
  float acc[E_EXP] = {};
  const f32x4* xrow = (const f32x4*)(x + (size_t)t * D_DIM);
#pragma unroll
  for (int i = 0; i < 4; ++i) {
    f32x4 xv = xrow[lane + 64 * i];
#pragma unroll
    for (int e = 0; e < E_EXP; ++e) {
      f32x4 gv = ((const f32x4*)g)[e * 256 + lane + 64 * i];
      acc[e] += xv[0] * gv[0] + xv[1] * gv[1] + xv[2] * gv[2] + xv[3] * gv[3];
    }
  }
#pragma unroll
  for (int e = 0; e < E_EXP; ++e)
#pragma unroll
    for (int off = 1; off < 64; off <<= 1)
      acc[e] += __shfl_xor(acc[e], off);
  if (lane == 0) {
    int i0 = 0; float v0 = acc[0];
    for (int e = 1; e < E_EXP; ++e) if (acc[e] > v0) { v0 = acc[e]; i0 = e; }
    int i1 = -1; float v1 = -1e30f;
    for (int e = 0; e < E_EXP; ++e) if (e != i0 && acc[e] > v1) { v1 = acc[e]; i1 = e; }
    float z = __expf(v1 - v0);
    tok_e[2 * t] = i0; tok_e[2 * t + 1] = i1;
    gatew[2 * t] = 1.f / (1.f + z); gatew[2 * t + 1] = z / (1.f + z);
    atomicAdd(&counts[i0], 1); atomicAdd(&counts[i1], 1);
  }
}

// ---------------- routing metadata ----------------
__global__ void scan_kernel(const int* __restrict__ counts, int* __restrict__ off,
                            int* __restrict__ mb2e, int* __restrict__ mb2row) {
  if (threadIdx.x == 0 && blockIdx.x == 0) {
    int acc = 0, mb = 0;
    for (int e = 0; e < E_EXP; ++e) {
      off[e] = acc;
      int nb = (counts[e] + BM - 1) / BM;
      for (int b = 0; b < nb; ++b) { mb2e[mb] = e; mb2row[mb] = acc + b * BM; ++mb; }
      acc += nb * BM;
    }
    off[E_EXP] = acc;
    for (; mb < MAXMB; ++mb) mb2e[mb] = -1;
  }
}

__global__ __launch_bounds__(256) void assign_kernel(const int* __restrict__ tok_e,
                                                     const int* __restrict__ off,
                                                     int* __restrict__ fill,
                                                     int* __restrict__ perm,
                                                     int* __restrict__ tok_slot) {
  int t = blockIdx.x * 256 + threadIdx.x;
  if (t >= T_TOK) return;
#pragma unroll
  for (int k = 0; k < 2; ++k) {
    int e = tok_e[2 * t + k];
    int pos = atomicAdd(&fill[e], 1);
    int slot = off[e] + pos;
    perm[slot] = t;
    tok_slot[2 * t + k] = slot;
  }
}

// ---------------- gather tokens -> contiguous bf16 rows per expert ----------------
__global__ __launch_bounds__(128) void gather_kernel(const float* __restrict__ x,
                                                     const int* __restrict__ off,
                                                     const int* __restrict__ counts,
                                                     const int* __restrict__ perm,
                                                     short* __restrict__ Xp) {
  int s = blockIdx.x, tid = threadIdx.x;
  int e = -1;
#pragma unroll
  for (int i = 0; i < E_EXP; ++i)
    if (s >= off[i] && s < off[i + 1]) { e = i; break; }
  bool valid = false; int t = 0;
  if (e >= 0) { int r = s - off[e]; if (r < counts[e]) { valid = true; t = perm[s]; } }
  s16x8 o;
  if (valid) {
    const f32x4* xr = (const f32x4*)(x + (size_t)t * D_DIM);
    f32x4 a = xr[tid * 2], b = xr[tid * 2 + 1];
    o[0] = bf16_of(a[0]); o[1] = bf16_of(a[1]); o[2] = bf16_of(a[2]); o[3] = bf16_of(a[3]);
    o[4] = bf16_of(b[0]); o[5] = bf16_of(b[1]); o[6] = bf16_of(b[2]); o[7] = bf16_of(b[3]);
  } else {
#pragma unroll
    for (int j = 0; j < 8; ++j) o[j] = 0;
  }
  *(s16x8*)(Xp + (size_t)s * D_DIM + tid * 8) = o;
}

// ---------------- GEMM: 256x256 tile, BK=32, 8 waves, triple-buffer LDS,
// prefetch distance 2 K-tiles, counted vmcnt(4) per K-tile boundary (T3+T4).
// LDS per K-tile: A 256x32 bf16 (16 KiB) + B 256x32 (16 KiB); rows 64 B,
// swizzle: quarter ^= (row>>1)&3 (conflict-free 8-lane groups, rule-21 both-sides).
// C[m][n] = sum_k A[m][k]*B[n][k], bf16 in, fp32 acc.
template <int K, int EPI>
__global__ __launch_bounds__(512) void gemm256(const short* __restrict__ A,
                                               const short* __restrict__ Bw,
                                               const int* __restrict__ mb2e,
                                               const int* __restrict__ mb2row,
                                               const float* __restrict__ biasA,
                                               const float* __restrict__ biasB,
                                               short* __restrict__ Out) {
  constexpr int NFULL = (EPI == 0) ? NP2 : D_DIM;
  constexpr int OUTLD = (EPI == 0) ? H_DIM : D_DIM;
  constexpr int KB = K * 2;          // row bytes
  constexpr int NT = K / 32;         // K-tiles

  const int mb = blockIdx.y;
  const int e = mb2e[mb];
  if (e < 0) return;
  const int row0 = mb2row[mb];
  const int bn = blockIdx.x;

  __shared__ alignas(16) char lds[3 * 32768];      // 96 KiB: 3 bufs x (A 16K | B 16K)

  const int tid = threadIdx.x;
  const int lane = tid & 63;
  const int wid = tid >> 6;          // 0..7
  const int wr = wid >> 2;           // 0..1  (128-row half)
  const int wc = wid & 3;            // 0..3  (64-col quarter)

  const char* gA = (const char*)(A + (size_t)row0 * K);
  const char* gB = (const char*)(Bw + ((size_t)e * NFULL + (size_t)bn * BM) * K);

  // staging: per round, thread covers row = rnd*128 + tid>>2, phys quarter tid&3
  const int srow0 = tid >> 2, spq = tid & 3;

  f32x4 acc[8][4] = {};

  auto stage = [&](int kt, int buf, int which) {   // which: 0=A, 1=B
    const char* g = which ? gB : gA;
    char* l = lds + buf * 32768 + which * 16384;
#pragma unroll
    for (int rnd = 0; rnd < 2; ++rnd) {
      const int row = rnd * 128 + srow0;
      const int lq = spq ^ ((row >> 1) & 3);
      gload16(g + (size_t)row * KB + kt * 64 + lq * 16,
              l + rnd * 8192 + tid * 16);          // = row*64 + spq*16 (linear dest)
    }
  };

  // prologue: stage tiles 0 and 1 (8 loads/thread), wait tile0's 4, barrier
  stage(0, 0, 0); stage(0, 0, 1);
  stage(1, 1, 0); stage(1, 1, 1);
  asm volatile("s_waitcnt vmcnt(4)" ::: "memory");
  __builtin_amdgcn_s_barrier();
  __builtin_amdgcn_sched_barrier(0);

  // ds_read addressing: row = base + f*16 + (lane&15); k-elems (lane>>4)*8
  const int qsw = (((lane >> 4) ^ ((lane >> 1) & 3)) << 4);  // swizzled quarter byte
  const int arow = wr * 128 + (lane & 15);
  const int brow = wc * 64 + (lane & 15);

  int bc = 0;   // t % 3
  int b2 = 2;   // (t+2) % 3
  for (int t = 0; t < NT; ++t) {
    const char* bufb = lds + bc * 32768;
    const char* pa = bufb + arow * 64 + qsw;
    const char* pb = bufb + 16384 + brow * 64 + qsw;
    s16x8 av[4], bv[4];
#pragma unroll
    for (int f = 0; f < 4; ++f) bv[f] = *(const s16x8*)(pb + f * 1024);
#pragma unroll
    for (int f = 0; f < 4; ++f) av[f] = *(const s16x8*)(pa + f * 1024);
    if (t + 2 < NT) stage(t + 2, b2, 0);
    __builtin_amdgcn_s_setprio(1);
#pragma unroll
    for (int mf = 0; mf < 4; ++mf)
#pragma unroll
      for (int nf = 0; nf < 4; ++nf)
        acc[mf][nf] = __builtin_amdgcn_mfma_f32_16x16x32_bf16(av[mf], bv[nf], acc[mf][nf], 0, 0, 0);
    __builtin_amdgcn_s_setprio(0);
    // phase 1: upper 64 rows of A half
#pragma unroll
    for (int f = 0; f < 4; ++f) av[f] = *(const s16x8*)(pa + (4 + f) * 1024);
    if (t + 2 < NT) stage(t + 2, b2, 1);
    __builtin_amdgcn_s_setprio(1);
#pragma unroll
    for (int mf = 0; mf < 4; ++mf)
#pragma unroll
      for (int nf = 0; nf < 4; ++nf)
        acc[4 + mf][nf] = __builtin_amdgcn_mfma_f32_16x16x32_bf16(av[mf], bv[nf], acc[4 + mf][nf], 0, 0, 0);
    __builtin_amdgcn_s_setprio(0);

    if (t < NT - 1) {
      __builtin_amdgcn_sched_barrier(0);
      if (t == NT - 2) asm volatile("s_waitcnt vmcnt(0)" ::: "memory");
      else             asm volatile("s_waitcnt vmcnt(4)" ::: "memory");
      __builtin_amdgcn_s_barrier();
      __builtin_amdgcn_sched_barrier(0);
    }
    bc = (bc == 2) ? 0 : bc + 1;
    b2 = (b2 == 2) ? 0 : b2 + 1;
  }

  // epilogue: C/D layout col=lane&15, row=(lane>>4)*4+j
  if constexpr (EPI == 0) {
#pragma unroll
    for (int mf = 0; mf < 8; ++mf) {
      const int mrow = row0 + wr * 128 + mf * 16 + ((lane >> 4) << 2);
#pragma unroll
      for (int p = 0; p < 2; ++p) {                // nf pair: 2p=w1-path, 2p+1=w2-path
        const int hcol = bn * 128 + wc * 32 + p * 16 + (lane & 15);
        const float bb1 = biasA[e * H_DIM + hcol];
        const float bb2 = biasB[e * H_DIM + hcol];
        const f32x4 a1 = acc[mf][2 * p], a2 = acc[mf][2 * p + 1];
#pragma unroll
        for (int j = 0; j < 4; ++j) {
          float x1 = a1[j] + bb1, x2 = a2[j] + bb2;
          float hv = x1 * (x2 / (1.f + __expf(-x2)));   // x1 * silu(x2)
          Out[(size_t)(mrow + j) * OUTLD + hcol] = bf16_of(hv);
        }
      }
    }
  } else {
#pragma unroll
    for (int mf = 0; mf < 8; ++mf) {
      const int mrow = row0 + wr * 128 + mf * 16 + ((lane >> 4) << 2);
#pragma unroll
      for (int nf = 0; nf < 4; ++nf) {
        const int col = bn * BM + wc * 64 + nf * 16 + (lane & 15);
        const float bb = biasA[e * D_DIM + col];
#pragma unroll
        for (int j = 0; j < 4; ++j)
          Out[(size_t)(mrow + j) * OUTLD + col] = bf16_of(acc[mf][nf][j] + bb);
      }
    }
  }
}

// ---------------- combine: out[t] = w0*ys[slot0] + w1*ys[slot1] ----------------
__global__ __launch_bounds__(128) void combine_kernel(const short* __restrict__ ysb,
                                                      const int* __restrict__ tok_slot,
                                                      const float* __restrict__ gatew,
                                                      float* __restrict__ out) {
  int t = blockIdx.x, tid = threadIdx.x;
  int s0 = tok_slot[2 * t], s1 = tok_slot[2 * t + 1];
  float w0 = gatew[2 * t], w1 = gatew[2 * t + 1];
  s16x8 a = *(const s16x8*)(ysb + (size_t)s0 * D_DIM + tid * 8);
  s16x8 b = *(const s16x8*)(ysb + (size_t)s1 * D_DIM + tid * 8);
  float* op = out + (size_t)t * D_DIM + tid * 8;
  f32x4 o0, o1;
#pragma unroll
  for (int j = 0; j < 4; ++j) o0[j] = w0 * f_of_bf16(a[j]) + w1 * f_of_bf16(b[j]);
#pragma unroll
  for (int j = 0; j < 4; ++j) o1[j] = w0 * f_of_bf16(a[4 + j]) + w1 * f_of_bf16(b[4 + j]);
  *(f32x4*)op = o0;
  *(f32x4*)(op + 4) = o1;
}

// ---------------- launcher ----------------
extern "C" void kernel_launch(void* const* d_in, const int* in_sizes, int n_in,
                              void* d_out, int out_size, void* d_ws, size_t ws_size,
                              hipStream_t stream) {
  const float* x  = (const float*)d_in[0];
  const float* gw = (const float*)d_in[1];
  const float* w1 = (const float*)d_in[2];
  const float* b1 = (const float*)d_in[3];
  const float* w2 = (const float*)d_in[4];
  const float* b2 = (const float*)d_in[5];
  const float* w3 = (const float*)d_in[6];
  const float* b3 = (const float*)d_in[7];
  float* out = (float*)d_out;

  char* ws = (char*)d_ws;
  size_t o = 0;
  short* w12b = (short*)(ws + o); o += (size_t)E_EXP * NP2 * D_DIM * 2;      //  67,108,864
  short* w3b  = (short*)(ws + o); o += (size_t)E_EXP * D_DIM * H_DIM * 2;    //  33,554,432
  short* Xp   = (short*)(ws + o); o += (size_t)CAP * D_DIM * 2;              //  37,748,736
  short* ysb  = Xp;                 // alias: Xp dead after gemm12, ysb written by gemm3
  short* hbuf = (short*)(ws + o); o += (size_t)CAP * H_DIM * 2;              //  75,497,472
  int* meta     = (int*)(ws + o);
  int* counts   = meta;             // 8
  int* fill     = meta + 8;         // 8
  int* offv     = meta + 16;        // 9 (pad to 16)
  int* mb2e     = meta + 32;        // 72 (pad to 80)
  int* mb2row   = meta + 112;       // 72 (pad to 80)
  int* tok_e    = meta + 192;       // 2T
  int* tok_slot = tok_e + 2 * T_TOK;
  int* perm     = tok_slot + 2 * T_TOK;             // CAP
  float* gatew  = (float*)(perm + CAP);             // 2T
  const size_t ws_needed = o + (192 + 4 * T_TOK + CAP + 2 * T_TOK) * sizeof(int);
  if (ws_size < ws_needed) return;   // fail validation loudly rather than corrupt

  hipMemsetAsync(counts, 0, 16 * sizeof(int), stream);  // counts + fill

  conv_w12<<<(E_EXP * NP2 * 256) / 256, 256, 0, stream>>>(w1, w2, w12b);
  conv_w3 <<<(E_EXP * D_DIM * (H_DIM / 4)) / 256, 256, 0, stream>>>(w3, w3b);
  gate_kernel<<<T_TOK / 4, 256, 0, stream>>>(x, gw, counts, tok_e, gatew);
  scan_kernel<<<1, 64, 0, stream>>>(counts, offv, mb2e, mb2row);
  assign_kernel<<<T_TOK / 256, 256, 0, stream>>>(tok_e, offv, fill, perm, tok_slot);
  gather_kernel<<<CAP, 128, 0, stream>>>(x, offv, counts, perm, Xp);
  gemm256<D_DIM, 0><<<dim3(NP2 / BM, MAXMB), 512, 0, stream>>>(Xp, w12b, mb2e, mb2row, b1, b2, hbuf);
  gemm256<H_DIM, 1><<<dim3(D_DIM / BM, MAXMB), 512, 0, stream>>>(hbuf, w3b, mb2e, mb2row, b3, b3, ysb);
  combine_kernel<<<T_TOK, 128, 0, stream>>>(ysb, tok_slot, gatew, out);
}

// Round 3
// 373.870 us; speedup vs baseline: 1.9458x; 1.6992x over previous
//
#include <hip/hip_runtime.h>
#include <hip/hip_bf16.h>
#include <stdint.h>

// Problem constants: B=4,S=2048 -> T=8192, D=1024, H=2048, E=8, topk=2
#define T_TOK   8192
#define D_DIM   1024
#define H_DIM   2048
#define E_EXP   8
#define NP2     4096                    // interleaved w1/w2 rows = 2*H
#define BM      256                     // GEMM M/N tile; expert regions 256-aligned
#define CAP     (2*T_TOK + E_EXP*BM)    // 18432 padded slots
#define MAXMB   (CAP/BM)                // 72 max m-blocks

using f32x4 = __attribute__((ext_vector_type(4))) float;
using s16x4 = __attribute__((ext_vector_type(4))) short;
using s16x8 = __attribute__((ext_vector_type(8))) short;   // 8 bf16 (MFMA A/B frag)

__device__ __forceinline__ short bf16_of(float f) {
  union { float f; unsigned u; } v; v.f = f;
  unsigned r = v.u + 0x7FFFu + ((v.u >> 16) & 1u);          // RNE
  return (short)(r >> 16);
}
__device__ __forceinline__ float f_of_bf16(short s) {
  union { unsigned u; float f; } v; v.u = ((unsigned)(unsigned short)s) << 16;
  return v.f;
}

__device__ __forceinline__ void gload16(const void* g, void* l) {
  __builtin_amdgcn_global_load_lds(
      (const __attribute__((address_space(1))) unsigned int*)g,
      (__attribute__((address_space(3))) unsigned int*)l, 16, 0, 0);
}

// ---------------- weight conversion ----------------
// w12b layout: [e][n'][k], n' = g*32 + half*16 + s -> (half?w2:w1)[e][g*16+s][k]
__global__ __launch_bounds__(256) void conv_w12(const float* __restrict__ w1,
                                                const float* __restrict__ w2,
                                                short* __restrict__ w12b) {
  int idx = blockIdx.x * 256 + threadIdx.x;        // over E*4096*256 f32x4 units
  int e = idx >> 20;
  int rem = idx & 0xFFFFF;
  int np = rem >> 8;
  int kc = rem & 255;
  int g = np >> 5, tt = np & 31, half = tt >> 4, srow = g * 16 + (tt & 15);
  const f32x4* src = (const f32x4*)(half ? w2 : w1) + ((size_t)e * H_DIM + srow) * 256 + kc;
  f32x4 v = *src;
  s16x4 o;
  o[0] = bf16_of(v[0]); o[1] = bf16_of(v[1]); o[2] = bf16_of(v[2]); o[3] = bf16_of(v[3]);
  ((s16x4*)w12b)[idx] = o;
}

__global__ __launch_bounds__(256) void conv_w3(const float* __restrict__ w3,
                                               short* __restrict__ w3b) {
  int idx = blockIdx.x * 256 + threadIdx.x;        // over E*1024*512 f32x4 units
  f32x4 v = ((const f32x4*)w3)[idx];
  s16x4 o;
  o[0] = bf16_of(v[0]); o[1] = bf16_of(v[1]); o[2] = bf16_of(v[2]); o[3] = bf16_of(v[3]);
  ((s16x4*)w3b)[idx] = o;
}

// ---------------- gating (NO atomics: counts done by hist_kernel) ----------------
__global__ __launch_bounds__(256) void gate_kernel(const float* __restrict__ x,
                                                   const float* __restrict__ gw,
                                                   int* __restrict__ tok_e,
                                                   float* __restrict__ gatew) {
  __shared__ float g[E_EXP * D_DIM];               // 32 KiB
  int tid = threadIdx.x;
  for (int i = tid; i < E_EXP * 256; i += 256)
    ((f32x4*)g)[i] = ((const f32x4*)gw)[i];
  __syncthreads();
  int w = tid >> 6, lane = tid & 63;
  int t = blockIdx.x * 4 + w;
  float acc[E_EXP] = {};
  const f32x4* xrow = (const f32x4*)(x + (size_t)t * D_DIM);
#pragma unroll
  for (int i = 0; i < 4; ++i) {
    f32x4 xv = xrow[lane + 64 * i];
#pragma unroll
    for (int e = 0; e < E_EXP; ++e) {
      f32x4 gv = ((const f32x4*)g)[e * 256 + lane + 64 * i];
      acc[e] += xv[0] * gv[0] + xv[1] * gv[1] + xv[2] * gv[2] + xv[3] * gv[3];
    }
  }
#pragma unroll
  for (int e = 0; e < E_EXP; ++e)
#pragma unroll
    for (int off = 1; off < 64; off <<= 1)
      acc[e] += __shfl_xor(acc[e], off);
  if (lane == 0) {
    int i0 = 0; float v0 = acc[0];
    for (int e = 1; e < E_EXP; ++e) if (acc[e] > v0) { v0 = acc[e]; i0 = e; }  // ties: lower idx
    int i1 = -1; float v1 = -1e30f;
    for (int e = 0; e < E_EXP; ++e) if (e != i0 && acc[e] > v1) { v1 = acc[e]; i1 = e; }
    float z = __expf(v1 - v0);
    tok_e[2 * t] = i0; tok_e[2 * t + 1] = i1;
    gatew[2 * t] = 1.f / (1.f + z); gatew[2 * t + 1] = z / (1.f + z);
  }
}

// ---------------- histogram: ballot -> LDS -> 8 atomics/block (128 total) ----------
__global__ __launch_bounds__(256) void hist_kernel(const int* __restrict__ tok_e,
                                                   int* __restrict__ counts) {
  __shared__ int bc[E_EXP];
  const int tid = threadIdx.x, lane = tid & 63;
  if (tid < E_EXP) bc[tid] = 0;
  __syncthreads();
  const int4 v = ((const int4*)tok_e)[blockIdx.x * 256 + tid];   // 4 entries/thread
#pragma unroll
  for (int e = 0; e < E_EXP; ++e) {
    int cnt = __popcll(__ballot(v.x == e)) + __popcll(__ballot(v.y == e)) +
              __popcll(__ballot(v.z == e)) + __popcll(__ballot(v.w == e));
    if (lane == 0 && cnt) atomicAdd(&bc[e], cnt);
  }
  __syncthreads();
  if (tid < E_EXP && bc[tid]) atomicAdd(&counts[tid], bc[tid]);
}

// ---------------- routing metadata ----------------
__global__ void scan_kernel(const int* __restrict__ counts, int* __restrict__ off,
                            int* __restrict__ mb2e, int* __restrict__ mb2row) {
  if (threadIdx.x == 0 && blockIdx.x == 0) {
    int acc = 0, mb = 0;
    for (int e = 0; e < E_EXP; ++e) {
      off[e] = acc;
      int nb = (counts[e] + BM - 1) / BM;
      for (int b = 0; b < nb; ++b) { mb2e[mb] = e; mb2row[mb] = acc + b * BM; ++mb; }
      acc += nb * BM;
    }
    off[E_EXP] = acc;
    for (; mb < MAXMB; ++mb) mb2e[mb] = -1;
  }
}

// ---------------- assign: wave ballot-rank + block LDS aggregation ----------------
// <=8 returning atomics per block (64 blocks -> <=512 total, was 16384 same-line).
__global__ __launch_bounds__(256) void assign_kernel(const int* __restrict__ tok_e,
                                                     const int* __restrict__ off,
                                                     int* __restrict__ fill,
                                                     int* __restrict__ perm,
                                                     int* __restrict__ tok_slot) {
  __shared__ int wcnt[4][E_EXP];
  __shared__ int wbase[4][E_EXP];
  const int tid = threadIdx.x, lane = tid & 63, wid = tid >> 6;
  if (tid < 32) wcnt[tid >> 3][tid & 7] = 0;
  __syncthreads();
  const int ent = blockIdx.x * 256 + tid;          // ent = 2*t + k
  const int e = tok_e[ent];
  int myrank = 0;
#pragma unroll
  for (int e0 = 0; e0 < E_EXP; ++e0) {
    unsigned long long m = __ballot(e == e0);
    if (e == e0) {
      myrank = __popcll(m & ((1ull << lane) - 1ull));
      if (myrank == 0) wcnt[wid][e0] = __popcll(m);
    }
  }
  __syncthreads();
  if (tid < E_EXP) {
    int tot = wcnt[0][tid] + wcnt[1][tid] + wcnt[2][tid] + wcnt[3][tid];
    int base = tot ? atomicAdd(&fill[tid], tot) : 0;
#pragma unroll
    for (int w = 0; w < 4; ++w) { wbase[w][tid] = base; base += wcnt[w][tid]; }
  }
  __syncthreads();
  const int slot = off[e] + wbase[wid][e] + myrank;
  perm[slot] = ent >> 1;
  tok_slot[ent] = slot;
}

// ---------------- gather tokens -> contiguous bf16 rows per expert ----------------
__global__ __launch_bounds__(128) void gather_kernel(const float* __restrict__ x,
                                                     const int* __restrict__ off,
                                                     const int* __restrict__ counts,
                                                     const int* __restrict__ perm,
                                                     short* __restrict__ Xp) {
  int s = blockIdx.x, tid = threadIdx.x;
  int e = -1;
#pragma unroll
  for (int i = 0; i < E_EXP; ++i)
    if (s >= off[i] && s < off[i + 1]) { e = i; break; }
  bool valid = false; int t = 0;
  if (e >= 0) { int r = s - off[e]; if (r < counts[e]) { valid = true; t = perm[s]; } }
  s16x8 o;
  if (valid) {
    const f32x4* xr = (const f32x4*)(x + (size_t)t * D_DIM);
    f32x4 a = xr[tid * 2], b = xr[tid * 2 + 1];
    o[0] = bf16_of(a[0]); o[1] = bf16_of(a[1]); o[2] = bf16_of(a[2]); o[3] = bf16_of(a[3]);
    o[4] = bf16_of(b[0]); o[5] = bf16_of(b[1]); o[6] = bf16_of(b[2]); o[7] = bf16_of(b[3]);
  } else {
#pragma unroll
    for (int j = 0; j < 8; ++j) o[j] = 0;
  }
  *(s16x8*)(Xp + (size_t)s * D_DIM + tid * 8) = o;
}

// ---------------- GEMM: 256x256 tile, BK=32, 8 waves, triple-buffer LDS,
// prefetch distance 2 K-tiles, counted vmcnt(4) per K-tile boundary (T3+T4).
template <int K, int EPI>
__global__ __launch_bounds__(512) void gemm256(const short* __restrict__ A,
                                               const short* __restrict__ Bw,
                                               const int* __restrict__ mb2e,
                                               const int* __restrict__ mb2row,
                                               const float* __restrict__ biasA,
                                               const float* __restrict__ biasB,
                                               short* __restrict__ Out) {
  constexpr int NFULL = (EPI == 0) ? NP2 : D_DIM;
  constexpr int OUTLD = (EPI == 0) ? H_DIM : D_DIM;
  constexpr int KB = K * 2;          // row bytes
  constexpr int NT = K / 32;         // K-tiles

  const int mb = blockIdx.y;
  const int e = mb2e[mb];
  if (e < 0) return;
  const int row0 = mb2row[mb];
  const int bn = blockIdx.x;

  __shared__ alignas(16) char lds[3 * 32768];      // 96 KiB: 3 bufs x (A 16K | B 16K)

  const int tid = threadIdx.x;
  const int lane = tid & 63;
  const int wid = tid >> 6;          // 0..7
  const int wr = wid >> 2;           // 0..1  (128-row half)
  const int wc = wid & 3;            // 0..3  (64-col quarter)

  const char* gA = (const char*)(A + (size_t)row0 * K);
  const char* gB = (const char*)(Bw + ((size_t)e * NFULL + (size_t)bn * BM) * K);

  const int srow0 = tid >> 2, spq = tid & 3;

  f32x4 acc[8][4] = {};

  auto stage = [&](int kt, int buf, int which) {   // which: 0=A, 1=B
    const char* g = which ? gB : gA;
    char* l = lds + buf * 32768 + which * 16384;
#pragma unroll
    for (int rnd = 0; rnd < 2; ++rnd) {
      const int row = rnd * 128 + srow0;
      const int lq = spq ^ ((row >> 1) & 3);
      gload16(g + (size_t)row * KB + kt * 64 + lq * 16,
              l + rnd * 8192 + tid * 16);          // = row*64 + spq*16 (linear dest)
    }
  };

  stage(0, 0, 0); stage(0, 0, 1);
  stage(1, 1, 0); stage(1, 1, 1);
  asm volatile("s_waitcnt vmcnt(4)" ::: "memory");
  __builtin_amdgcn_s_barrier();
  __builtin_amdgcn_sched_barrier(0);

  const int qsw = (((lane >> 4) ^ ((lane >> 1) & 3)) << 4);  // swizzled quarter byte
  const int arow = wr * 128 + (lane & 15);
  const int brow = wc * 64 + (lane & 15);

  int bc = 0;   // t % 3
  int b2 = 2;   // (t+2) % 3
  for (int t = 0; t < NT; ++t) {
    const char* bufb = lds + bc * 32768;
    const char* pa = bufb + arow * 64 + qsw;
    const char* pb = bufb + 16384 + brow * 64 + qsw;
    s16x8 av[4], bv[4];
#pragma unroll
    for (int f = 0; f < 4; ++f) bv[f] = *(const s16x8*)(pb + f * 1024);
#pragma unroll
    for (int f = 0; f < 4; ++f) av[f] = *(const s16x8*)(pa + f * 1024);
    if (t + 2 < NT) stage(t + 2, b2, 0);
    __builtin_amdgcn_s_setprio(1);
#pragma unroll
    for (int mf = 0; mf < 4; ++mf)
#pragma unroll
      for (int nf = 0; nf < 4; ++nf)
        acc[mf][nf] = __builtin_amdgcn_mfma_f32_16x16x32_bf16(av[mf], bv[nf], acc[mf][nf], 0, 0, 0);
    __builtin_amdgcn_s_setprio(0);
#pragma unroll
    for (int f = 0; f < 4; ++f) av[f] = *(const s16x8*)(pa + (4 + f) * 1024);
    if (t + 2 < NT) stage(t + 2, b2, 1);
    __builtin_amdgcn_s_setprio(1);
#pragma unroll
    for (int mf = 0; mf < 4; ++mf)
#pragma unroll
      for (int nf = 0; nf < 4; ++nf)
        acc[4 + mf][nf] = __builtin_amdgcn_mfma_f32_16x16x32_bf16(av[mf], bv[nf], acc[4 + mf][nf], 0, 0, 0);
    __builtin_amdgcn_s_setprio(0);

    if (t < NT - 1) {
      __builtin_amdgcn_sched_barrier(0);
      if (t == NT - 2) asm volatile("s_waitcnt vmcnt(0)" ::: "memory");
      else             asm volatile("s_waitcnt vmcnt(4)" ::: "memory");
      __builtin_amdgcn_s_barrier();
      __builtin_amdgcn_sched_barrier(0);
    }
    bc = (bc == 2) ? 0 : bc + 1;
    b2 = (b2 == 2) ? 0 : b2 + 1;
  }

  // epilogue: C/D layout col=lane&15, row=(lane>>4)*4+j
  if constexpr (EPI == 0) {
#pragma unroll
    for (int mf = 0; mf < 8; ++mf) {
      const int mrow = row0 + wr * 128 + mf * 16 + ((lane >> 4) << 2);
#pragma unroll
      for (int p = 0; p < 2; ++p) {                // nf pair: 2p=w1-path, 2p+1=w2-path
        const int hcol = bn * 128 + wc * 32 + p * 16 + (lane & 15);
        const float bb1 = biasA[e * H_DIM + hcol];
        const float bb2 = biasB[e * H_DIM + hcol];
        const f32x4 a1 = acc[mf][2 * p], a2 = acc[mf][2 * p + 1];
#pragma unroll
        for (int j = 0; j < 4; ++j) {
          float x1 = a1[j] + bb1, x2 = a2[j] + bb2;
          float hv = x1 * (x2 / (1.f + __expf(-x2)));   // x1 * silu(x2)
          Out[(size_t)(mrow + j) * OUTLD + hcol] = bf16_of(hv);
        }
      }
    }
  } else {
#pragma unroll
    for (int mf = 0; mf < 8; ++mf) {
      const int mrow = row0 + wr * 128 + mf * 16 + ((lane >> 4) << 2);
#pragma unroll
      for (int nf = 0; nf < 4; ++nf) {
        const int col = bn * BM + wc * 64 + nf * 16 + (lane & 15);
        const float bb = biasA[e * D_DIM + col];
#pragma unroll
        for (int j = 0; j < 4; ++j)
          Out[(size_t)(mrow + j) * OUTLD + col] = bf16_of(acc[mf][nf][j] + bb);
      }
    }
  }
}

// ---------------- combine: out[t] = w0*ys[slot0] + w1*ys[slot1] ----------------
__global__ __launch_bounds__(128) void combine_kernel(const short* __restrict__ ysb,
                                                      const int* __restrict__ tok_slot,
                                                      const float* __restrict__ gatew,
                                                      float* __restrict__ out) {
  int t = blockIdx.x, tid = threadIdx.x;
  int s0 = tok_slot[2 * t], s1 = tok_slot[2 * t + 1];
  float w0 = gatew[2 * t], w1 = gatew[2 * t + 1];
  s16x8 a = *(const s16x8*)(ysb + (size_t)s0 * D_DIM + tid * 8);
  s16x8 b = *(const s16x8*)(ysb + (size_t)s1 * D_DIM + tid * 8);
  float* op = out + (size_t)t * D_DIM + tid * 8;
  f32x4 o0, o1;
#pragma unroll
  for (int j = 0; j < 4; ++j) o0[j] = w0 * f_of_bf16(a[j]) + w1 * f_of_bf16(b[j]);
#pragma unroll
  for (int j = 0; j < 4; ++j) o1[j] = w0 * f_of_bf16(a[4 + j]) + w1 * f_of_bf16(b[4 + j]);
  *(f32x4*)op = o0;
  *(f32x4*)(op + 4) = o1;
}

// ---------------- launcher ----------------
extern "C" void kernel_launch(void* const* d_in, const int* in_sizes, int n_in,
                              void* d_out, int out_size, void* d_ws, size_t ws_size,
                              hipStream_t stream) {
  const float* x  = (const float*)d_in[0];
  const float* gw = (const float*)d_in[1];
  const float* w1 = (const float*)d_in[2];
  const float* b1 = (const float*)d_in[3];
  const float* w2 = (const float*)d_in[4];
  const float* b2 = (const float*)d_in[5];
  const float* w3 = (const float*)d_in[6];
  const float* b3 = (const float*)d_in[7];
  float* out = (float*)d_out;

  char* ws = (char*)d_ws;
  size_t o = 0;
  short* w12b = (short*)(ws + o); o += (size_t)E_EXP * NP2 * D_DIM * 2;      //  67,108,864
  short* w3b  = (short*)(ws + o); o += (size_t)E_EXP * D_DIM * H_DIM * 2;    //  33,554,432
  short* Xp   = (short*)(ws + o); o += (size_t)CAP * D_DIM * 2;              //  37,748,736
  short* ysb  = Xp;                 // alias: Xp dead after gemm12, ysb written by gemm3
  short* hbuf = (short*)(ws + o); o += (size_t)CAP * H_DIM * 2;              //  75,497,472
  int* meta     = (int*)(ws + o);
  int* counts   = meta;             // 8
  int* fill     = meta + 8;         // 8
  int* offv     = meta + 16;        // 9 (pad to 16)
  int* mb2e     = meta + 32;        // 72 (pad to 80)
  int* mb2row   = meta + 112;       // 72 (pad to 80)
  int* tok_e    = meta + 192;       // 2T
  int* tok_slot = tok_e + 2 * T_TOK;
  int* perm     = tok_slot + 2 * T_TOK;             // CAP
  float* gatew  = (float*)(perm + CAP);             // 2T
  const size_t ws_needed = o + (192 + 4 * T_TOK + CAP + 2 * T_TOK) * sizeof(int);
  if (ws_size < ws_needed) return;   // fail validation loudly rather than corrupt

  hipMemsetAsync(counts, 0, 16 * sizeof(int), stream);  // counts + fill

  conv_w12<<<(E_EXP * NP2 * 256) / 256, 256, 0, stream>>>(w1, w2, w12b);
  conv_w3 <<<(E_EXP * D_DIM * (H_DIM / 4)) / 256, 256, 0, stream>>>(w3, w3b);
  gate_kernel<<<T_TOK / 4, 256, 0, stream>>>(x, gw, tok_e, gatew);
  hist_kernel<<<(2 * T_TOK) / 1024, 256, 0, stream>>>(tok_e, counts);
  scan_kernel<<<1, 64, 0, stream>>>(counts, offv, mb2e, mb2row);
  assign_kernel<<<(2 * T_TOK) / 256, 256, 0, stream>>>(tok_e, offv, fill, perm, tok_slot);
  gather_kernel<<<CAP, 128, 0, stream>>>(x, offv, counts, perm, Xp);
  gemm256<D_DIM, 0><<<dim3(NP2 / BM, MAXMB), 512, 0, stream>>>(Xp, w12b, mb2e, mb2row, b1, b2, hbuf);
  gemm256<H_DIM, 1><<<dim3(D_DIM / BM, MAXMB), 512, 0, stream>>>(hbuf, w3b, mb2e, mb2row, b3, b3, ysb);
  combine_kernel<<<T_TOK, 128, 0, stream>>>(ysb, tok_slot, gatew, out);
}